// Round 1
// baseline (38.908 us; speedup 1.0000x reference)
//
#include <hip/hip_runtime.h>

#define BROWS 16384
#define NCLASS 1000
#define IGNORE_INDEX (-100)

// One wave (64 lanes) per row. Each row runs 3 dependent stages:
//   rank(t) = #{j: p[j] > p[t]} + #{j: p[j] == p[t] && j < t}
// which equals the position of t in a stable descending argsort (the
// reference's torch.topk / jnp.argsort(-p) semantics, including ties).
__global__ __launch_bounds__(256) void TopKBaseLoss_80281528697452_kernel(
    const float* __restrict__ x0,
    const float* __restrict__ x1,
    const float* __restrict__ x2,
    const int*   __restrict__ target,
    int*         __restrict__ out)
{
    const int gid  = blockIdx.x * blockDim.x + threadIdx.x;
    const int row  = gid >> 6;          // one wave per row
    const int lane = threadIdx.x & 63;
    if (row >= BROWS) return;

    int t = target[row];                // uniform across the wave
    if (lane == 0) out[row] = t;        // output 0: the original target

    const float* xs0 = x0 + (long)row * NCLASS;
    const float* xs1 = x1 + (long)row * NCLASS;
    const float* xs2 = x2 + (long)row * NCLASS;
    const float* stages[3] = {xs0, xs1, xs2};

    #pragma unroll
    for (int s = 0; s < 3; ++s) {
        int nt;
        if (t < 0 || t >= NCLASS) {
            nt = IGNORE_INDEX;          // target not present in argsort -> ignore
        } else {
            const float* __restrict__ x = stages[s];
            const float v = x[t];       // uniform broadcast load
            int cnt = 0;
            #pragma unroll 4
            for (int j = lane; j < NCLASS; j += 64) {
                const float xv = x[j];
                cnt += (xv > v) || (xv == v && j < t);
            }
            // 64-lane butterfly reduce; every lane ends with the full sum
            #pragma unroll
            for (int off = 32; off > 0; off >>= 1)
                cnt += __shfl_xor(cnt, off, 64);
            nt = cnt;
        }
        t = nt;                         // uniform (butterfly gives all lanes the sum)
        if (lane == 0) out[(s + 1) * BROWS + row] = t;
    }
}

extern "C" void kernel_launch(void* const* d_in, const int* in_sizes, int n_in,
                              void* d_out, int out_size, void* d_ws, size_t ws_size,
                              hipStream_t stream) {
    const float* x0     = (const float*)d_in[0];
    const float* x1     = (const float*)d_in[1];
    const float* x2     = (const float*)d_in[2];
    // d_in[3] (x3) is never used by the reference's outputs.
    const int*   target = (const int*)d_in[4];
    int*         out    = (int*)d_out;

    // One wave per row, 4 waves per 256-thread block.
    const int waves_per_block = 256 / 64;
    const int grid = (BROWS + waves_per_block - 1) / waves_per_block;
    TopKBaseLoss_80281528697452_kernel<<<grid, 256, 0, stream>>>(x0, x1, x2, target, out);
}